// Round 9
// baseline (328.752 us; speedup 1.0000x reference)
//
#include <hip/hip_runtime.h>
#include <stdint.h>

// B=8, W=1024, D=1024, H=16, KD=VD=64
// QK buffer: rows = token (8192), cols = proj*1024 + h*64 + d (2048; Q,K only, bf16)
// Vt[bh][d][m] fp16, written transposed from the GEMM epilogue.
// Q pre-scaled by 0.125*log2(e) (softmax in exp2 domain).
// attn: ZERO LDS, ZERO barriers — K and V^T MFMA fragments are loaded directly
// from global (L2-resident via XCD swizzle); P stays in registers (S^T C-layout
// == 16x16x16f16 B-frag layout). S^T seeded with -10 so P=exp2(s-10) < fp16 max.

using bf16x8 = __attribute__((ext_vector_type(8))) __bf16;
using f32x4  = __attribute__((ext_vector_type(4))) float;
using f16x4  = __attribute__((ext_vector_type(4))) _Float16;

union frag_u  { uint4 u4; bf16x8 f; };
union vfrag_u { uint2 u2; f16x4 f; };
union pfrag_u { unsigned int u[2]; f16x4 f; };

__device__ inline unsigned short f2bf(float x){
  unsigned int u = __float_as_uint(x);
  u += 0x7fffu + ((u >> 16) & 1u);      // round-to-nearest-even
  return (unsigned short)(u >> 16);
}

__device__ inline unsigned int pkrtz_u32(float a, float b){
  auto r = __builtin_amdgcn_cvt_pkrtz(a, b);   // __fp16 ext_vector(2)
  unsigned int u; __builtin_memcpy(&u, &r, 4); return u;
}

__device__ inline void gl_lds16(const void* g, void* l){
  __builtin_amdgcn_global_load_lds(
      (const __attribute__((address_space(1))) void*)g,
      (__attribute__((address_space(3))) void*)l, 16, 0, 0);
}

// ---------------- kernel 1: fused input & weight cast ----------------
// blocks [0,8192): X fp32->bf16.  blocks [8192,8960): W transpose+cast.
__global__ void cast_all(const float* __restrict__ X,
                         const float* __restrict__ Wq, const float* __restrict__ Wk,
                         const float* __restrict__ Wv,
                         unsigned short* __restrict__ Xb,
                         unsigned short* __restrict__ Wt){
  __shared__ float tile[64][65];
  int bid = blockIdx.x;
  if (bid < 8192){
    int i = (bid * 256 + threadIdx.x) * 4;
    float4 v = *(const float4*)(X + i);
    ushort4 o;
    o.x = f2bf(v.x); o.y = f2bf(v.y); o.z = f2bf(v.z); o.w = f2bf(v.w);
    *(ushort4*)(Xb + i) = o;
    return;
  }
  int id = bid - 8192;            // 0..767
  int proj = id >> 8;
  int rem  = id & 255;
  int kt = rem & 15, nt = rem >> 4;
  const float* Wsrc = (proj == 0) ? Wq : ((proj == 1) ? Wk : Wv);
  int k0 = kt * 64, n0 = nt * 64;
  int tx = threadIdx.x & 63, ty = threadIdx.x >> 6;   // ty 0..3
  for (int i = 0; i < 16; i++){
    int k = i * 4 + ty;
    tile[k][tx] = Wsrc[(k0 + k) * 1024 + n0 + tx];
  }
  __syncthreads();
  for (int i = 0; i < 16; i++){
    int n = i * 4 + ty;
    Wt[(proj * 1024 + n0 + n) * 1024 + k0 + tx] = f2bf(tile[tx][n]);
  }
}

// ---------------- kernel 2: fused QKV GEMM (m97 structure) ----------------
// n<1024 (Q): *0.125*log2(e) -> QK stride 2048 (bf16)
// 1024<=n<2048 (K): -> QK stride 2048 (bf16)
// n>=2048 (V): transposed -> Vt[bh][d][m] (fp16)
__global__ void gemm_qkv(const unsigned short* __restrict__ Xb,
                         const unsigned short* __restrict__ Wt,
                         unsigned short* __restrict__ QK,
                         unsigned short* __restrict__ Vt){
  __shared__ __align__(16) unsigned short Abuf[128 * 64];
  __shared__ __align__(16) unsigned short Bbuf[128 * 64];
  int bid = blockIdx.x;                 // 1536
  int bx = bid % 24, by = bid / 24;     // bx: n-tile, by: m-tile
  int w = threadIdx.x >> 6, lane = threadIdx.x & 63;
  int g = lane >> 4, li = lane & 15;
  int lrow = lane >> 3, lcol = lane & 7;
  int wm = (w >> 1) * 64, wn = (w & 1) * 64;
  f32x4 acc[4][4] = {};

  for (int k0 = 0; k0 < 1024; k0 += 64){
    __syncthreads();
    for (int i = 0; i < 4; i++){
      int idx = w * 4 + i;              // 0..15
      int row = idx * 8 + lrow;         // 0..127
      gl_lds16(Xb + (by * 128 + row) * 1024 + k0 + lcol * 8, Abuf + idx * 512);
      gl_lds16(Wt + (bx * 128 + row) * 1024 + k0 + lcol * 8, Bbuf + idx * 512);
    }
    __syncthreads();
    for (int c = 0; c < 2; c++){
      frag_u a[4], b[4];
      for (int i = 0; i < 4; i++)
        a[i].u4 = *(const uint4*)(Abuf + (wm + i * 16 + li) * 64 + c * 32 + g * 8);
      for (int j = 0; j < 4; j++)
        b[j].u4 = *(const uint4*)(Bbuf + (wn + j * 16 + li) * 64 + c * 32 + g * 8);
      for (int i = 0; i < 4; i++)
        for (int j = 0; j < 4; j++)
          acc[i][j] = __builtin_amdgcn_mfma_f32_16x16x32_bf16(a[i].f, b[j].f, acc[i][j], 0, 0, 0);
    }
  }
  if (bx >= 16){
    // V tiles: transposed fp16 into Vt[(b*16+h)*64*1024 + d*1024 + m]
    for (int i = 0; i < 4; i++){
      int row = by * 128 + wm + i * 16 + g * 4;     // token; r -> consecutive m
      int bb = row >> 10, m = row & 1023;
      for (int j = 0; j < 4; j++){
        int vc = bx * 128 + wn + j * 16 + li - 2048;  // v-column 0..1023
        int hh = vc >> 6, dd = vc & 63;
        uint2 cv;
        cv.x = pkrtz_u32(acc[i][j][0], acc[i][j][1]);
        cv.y = pkrtz_u32(acc[i][j][2], acc[i][j][3]);
        *(uint2*)(Vt + ((size_t)(bb * 16 + hh) * 64 + dd) * 1024 + m) = cv;
      }
    }
  } else {
    float sc = (bx < 8) ? 0.1803368801111f : 1.0f;   // 0.125 * log2(e) on Q only
    for (int i = 0; i < 4; i++){
      int row = by * 128 + wm + i * 16 + g * 4;
      for (int j = 0; j < 4; j++){
        int col = bx * 128 + wn + j * 16 + li;
        for (int r = 0; r < 4; r++)
          QK[(size_t)(row + r) * 2048 + col] = f2bf(acc[i][j][r] * sc);
      }
    }
  }
}

// ---------------- kernel 3: flash attention, LDS-free ----------------
// block = (b, h, qb): 4 waves x 32 q = 128 q per block; m-tiles of 64.
// XCD swizzle: bh = id&127 so q-blocks of one (b,h) share id%8 (same XCD L2).
// No __shared__, no barriers: K/V^T fragments load straight from global (L2).
__global__ __launch_bounds__(256) void attn(const unsigned short* __restrict__ QK,
                                            const unsigned short* __restrict__ Vt,
                                            float* __restrict__ Out){
  int id = blockIdx.x;                  // 1024
  int bh = id & 127, qb = id >> 7;
  int b = bh >> 4, h = bh & 15;
  int w = threadIdx.x >> 6, lane = threadIdx.x & 63;
  int g = lane >> 4, li = lane & 15;

  // Q B-frags (bf16): lane li holds col q, k = c*32 + g*8 + j
  frag_u qf[2][2];
  for (int u = 0; u < 2; u++){
    int tok = b * 1024 + qb * 128 + w * 32 + u * 16 + li;
    const unsigned short* qp = QK + (size_t)tok * 2048 + h * 64 + g * 8;
    qf[u][0].u4 = *(const uint4*)(qp);
    qf[u][1].u4 = *(const uint4*)(qp + 32);
  }

  f32x4 o[2][4] = {};          // O^T tiles: row v = tv*16+g*4+r, col q
  float psum[2] = {0.f, 0.f};  // per-lane softmax denoms (biased by 2^-10, cancels)
  const f32x4 bias = {-10.f, -10.f, -10.f, -10.f};   // fp16-overflow guard

  // Per-lane operand base pointers (row picked by lane, col by lane group):
  // K A-frag row = m0 + t*16 + li, k-col = c*32 + g*8   (dwordx4)
  const unsigned short* Kp = QK + (size_t)b * 1024 * 2048 + 1024 + h * 64
                           + (size_t)li * 2048 + g * 8;
  // V^T A-frag row = tv*16 + li, m-col = m0 + t*16 + g*4 (dwordx2)
  const unsigned short* Vp = Vt + (size_t)bh * 65536 + (size_t)li * 1024 + g * 4;

  for (int mt = 0; mt < 16; mt++){
    int m0 = mt * 64;

    // S^T = K Q^T - 10 : A-frag = K rows (m) direct from global, B-frag = Q (regs)
    f32x4 s[2][4];
    frag_u kf[4][2];
    for (int t = 0; t < 4; t++)
      for (int c = 0; c < 2; c++)
        kf[t][c].u4 = *(const uint4*)(Kp + (size_t)(m0 + t * 16) * 2048 + c * 32);
    for (int u = 0; u < 2; u++)
      for (int t = 0; t < 4; t++)
        s[u][t] = bias;
    for (int t = 0; t < 4; t++){
      for (int c = 0; c < 2; c++){
        s[0][t] = __builtin_amdgcn_mfma_f32_16x16x32_bf16(kf[t][c].f, qf[0][c].f, s[0][t], 0, 0, 0);
        s[1][t] = __builtin_amdgcn_mfma_f32_16x16x32_bf16(kf[t][c].f, qf[1][c].f, s[1][t], 0, 0, 0);
      }
    }

    // V^T fragments for this m-tile (issue early; independent of S)
    vfrag_u vf[4][4];
    for (int tv = 0; tv < 4; tv++)
      for (int t = 0; t < 4; t++)
        vf[tv][t].u2 = *(const uint2*)(Vp + (size_t)tv * 16 * 1024 + m0 + t * 16);

    // P = exp2(S^T); lane holds P[q][m = t*16 + g*4 + r] == B-frag(k = g*4+e) of
    // mfma_f32_16x16x16f16 for k-chunk t. Pack straight into registers.
    pfrag_u pf[2][4];
    for (int u = 0; u < 2; u++){
      for (int t = 0; t < 4; t++){
        float p0 = __builtin_exp2f(s[u][t][0]);
        float p1 = __builtin_exp2f(s[u][t][1]);
        float p2 = __builtin_exp2f(s[u][t][2]);
        float p3 = __builtin_exp2f(s[u][t][3]);
        psum[u] += (p0 + p1) + (p2 + p3);
        pf[u][t].u[0] = pkrtz_u32(p0, p1);
        pf[u][t].u[1] = pkrtz_u32(p2, p3);
      }
    }

    // O^T += V^T P^T : A-frag = V^T (regs, from global), B-frag = pf (regs)
    for (int tv = 0; tv < 4; tv++){
      for (int t = 0; t < 4; t++){
        o[0][tv] = __builtin_amdgcn_mfma_f32_16x16x16f16(vf[tv][t].f, pf[0][t].f, o[0][tv], 0, 0, 0);
        o[1][tv] = __builtin_amdgcn_mfma_f32_16x16x16f16(vf[tv][t].f, pf[1][t].f, o[1][tv], 0, 0, 0);
      }
    }
  }

  // softmax denominator: in-lane partials + across the 4 g-groups
  for (int u = 0; u < 2; u++){
    psum[u] += __shfl_xor(psum[u], 16);
    psum[u] += __shfl_xor(psum[u], 32);
  }

  // epilogue: lane holds O^T[v = tv*16+g*4+r][q] -> Out[b,q,h,v]; v contiguous
  for (int u = 0; u < 2; u++){
    float inv = 1.f / psum[u];
    int tok = b * 1024 + qb * 128 + w * 32 + u * 16 + li;
    float* op = Out + (size_t)tok * 1024 + h * 64 + g * 4;
    for (int tv = 0; tv < 4; tv++){
      float4 v4;
      v4.x = o[u][tv][0] * inv; v4.y = o[u][tv][1] * inv;
      v4.z = o[u][tv][2] * inv; v4.w = o[u][tv][3] * inv;
      *(float4*)(op + tv * 16) = v4;
    }
  }
}

extern "C" void kernel_launch(void* const* d_in, const int* in_sizes, int n_in,
                              void* d_out, int out_size, void* d_ws, size_t ws_size,
                              hipStream_t stream) {
  const float* X  = (const float*)d_in[0];
  const float* Wq = (const float*)d_in[1];
  const float* Wk = (const float*)d_in[2];
  const float* Wv = (const float*)d_in[3];
  float* Out = (float*)d_out;
  char* ws = (char*)d_ws;
  // workspace layout (bytes): Xb 16MB | Wt 6MB | QK 32MB | Vt 16MB  (total 70MB)
  unsigned short* Xb = (unsigned short*)(ws);
  unsigned short* Wt = (unsigned short*)(ws + (size_t)16 * 1024 * 1024);
  unsigned short* QK = (unsigned short*)(ws + (size_t)22 * 1024 * 1024);
  unsigned short* Vt = (unsigned short*)(ws + (size_t)54 * 1024 * 1024);

  cast_all<<<8960, 256, 0, stream>>>(X, Wq, Wk, Wv, Xb, Wt);
  gemm_qkv<<<1536, 256, 0, stream>>>(Xb, Wt, QK, Vt);
  attn    <<<1024, 256, 0, stream>>>(QK, Vt, Out);
}

// Round 10
// 217.162 us; speedup vs baseline: 1.5139x; 1.5139x over previous
//
#include <hip/hip_runtime.h>
#include <stdint.h>

// B=8, W=1024, D=1024, H=16, KD=VD=64
// QK buffer: rows = token (8192), cols = proj*1024 + h*64 + d (2048; Q,K only, bf16)
// Vt[bh][d][m] fp16, written transposed from the GEMM epilogue.
// Q pre-scaled by 0.125*log2(e) (softmax in exp2 domain).
// attn: single-buffered LDS staging (best measured structure), P in registers
// (S^T C-layout == 16x16x16f16 B-frag layout), 2048 blocks for 8 blocks/CU.
// S^T accumulator seeded with -10 so P=exp2(s-10) stays below fp16 max.

using bf16x8 = __attribute__((ext_vector_type(8))) __bf16;
using f32x4  = __attribute__((ext_vector_type(4))) float;
using f16x4  = __attribute__((ext_vector_type(4))) _Float16;

union frag_u  { uint4 u4; bf16x8 f; };
union vfrag_u { uint2 u2; f16x4 f; };
union pfrag_u { unsigned int u[2]; f16x4 f; };

__device__ inline unsigned short f2bf(float x){
  unsigned int u = __float_as_uint(x);
  u += 0x7fffu + ((u >> 16) & 1u);      // round-to-nearest-even
  return (unsigned short)(u >> 16);
}

__device__ inline unsigned int pkrtz_u32(float a, float b){
  auto r = __builtin_amdgcn_cvt_pkrtz(a, b);   // __fp16 ext_vector(2)
  unsigned int u; __builtin_memcpy(&u, &r, 4); return u;
}

__device__ inline void gl_lds16(const void* g, void* l){
  __builtin_amdgcn_global_load_lds(
      (const __attribute__((address_space(1))) void*)g,
      (__attribute__((address_space(3))) void*)l, 16, 0, 0);
}

// ---------------- kernel 1: fused input & weight cast ----------------
// blocks [0,8192): X fp32->bf16.  blocks [8192,8960): W transpose+cast.
__global__ void cast_all(const float* __restrict__ X,
                         const float* __restrict__ Wq, const float* __restrict__ Wk,
                         const float* __restrict__ Wv,
                         unsigned short* __restrict__ Xb,
                         unsigned short* __restrict__ Wt){
  __shared__ float tile[64][65];
  int bid = blockIdx.x;
  if (bid < 8192){
    int i = (bid * 256 + threadIdx.x) * 4;
    float4 v = *(const float4*)(X + i);
    ushort4 o;
    o.x = f2bf(v.x); o.y = f2bf(v.y); o.z = f2bf(v.z); o.w = f2bf(v.w);
    *(ushort4*)(Xb + i) = o;
    return;
  }
  int id = bid - 8192;            // 0..767
  int proj = id >> 8;
  int rem  = id & 255;
  int kt = rem & 15, nt = rem >> 4;
  const float* Wsrc = (proj == 0) ? Wq : ((proj == 1) ? Wk : Wv);
  int k0 = kt * 64, n0 = nt * 64;
  int tx = threadIdx.x & 63, ty = threadIdx.x >> 6;   // ty 0..3
  for (int i = 0; i < 16; i++){
    int k = i * 4 + ty;
    tile[k][tx] = Wsrc[(k0 + k) * 1024 + n0 + tx];
  }
  __syncthreads();
  for (int i = 0; i < 16; i++){
    int n = i * 4 + ty;
    Wt[(proj * 1024 + n0 + n) * 1024 + k0 + tx] = f2bf(tile[tx][n]);
  }
}

// ---------------- kernel 2: fused QKV GEMM (m97 structure) ----------------
// n<1024 (Q): *0.125*log2(e) -> QK stride 2048 (bf16)
// 1024<=n<2048 (K): -> QK stride 2048 (bf16)
// n>=2048 (V): transposed -> Vt[bh][d][m] (fp16)
// XCD swizzle: bid = bx*64 + by, so the 24 blocks sharing one Xb row-tile
// (same by) are spaced 64 apart -> same bid%8 -> same XCD L2 (Xb fills 1x).
__global__ void gemm_qkv(const unsigned short* __restrict__ Xb,
                         const unsigned short* __restrict__ Wt,
                         unsigned short* __restrict__ QK,
                         unsigned short* __restrict__ Vt){
  __shared__ __align__(16) unsigned short Abuf[128 * 64];
  __shared__ __align__(16) unsigned short Bbuf[128 * 64];
  int bid = blockIdx.x;                 // 1536
  int bx = bid >> 6, by = bid & 63;     // bx: n-tile (24), by: m-tile (64)
  int w = threadIdx.x >> 6, lane = threadIdx.x & 63;
  int g = lane >> 4, li = lane & 15;
  int lrow = lane >> 3, lcol = lane & 7;
  int wm = (w >> 1) * 64, wn = (w & 1) * 64;
  f32x4 acc[4][4] = {};

  for (int k0 = 0; k0 < 1024; k0 += 64){
    __syncthreads();
    for (int i = 0; i < 4; i++){
      int idx = w * 4 + i;              // 0..15
      int row = idx * 8 + lrow;         // 0..127
      gl_lds16(Xb + (by * 128 + row) * 1024 + k0 + lcol * 8, Abuf + idx * 512);
      gl_lds16(Wt + (bx * 128 + row) * 1024 + k0 + lcol * 8, Bbuf + idx * 512);
    }
    __syncthreads();
    for (int c = 0; c < 2; c++){
      frag_u a[4], b[4];
      for (int i = 0; i < 4; i++)
        a[i].u4 = *(const uint4*)(Abuf + (wm + i * 16 + li) * 64 + c * 32 + g * 8);
      for (int j = 0; j < 4; j++)
        b[j].u4 = *(const uint4*)(Bbuf + (wn + j * 16 + li) * 64 + c * 32 + g * 8);
      for (int i = 0; i < 4; i++)
        for (int j = 0; j < 4; j++)
          acc[i][j] = __builtin_amdgcn_mfma_f32_16x16x32_bf16(a[i].f, b[j].f, acc[i][j], 0, 0, 0);
    }
  }
  if (bx >= 16){
    // V tiles: transposed fp16 into Vt[(b*16+h)*64*1024 + d*1024 + m]
    for (int i = 0; i < 4; i++){
      int row = by * 128 + wm + i * 16 + g * 4;     // token; r -> consecutive m
      int bb = row >> 10, m = row & 1023;
      for (int j = 0; j < 4; j++){
        int vc = bx * 128 + wn + j * 16 + li - 2048;  // v-column 0..1023
        int hh = vc >> 6, dd = vc & 63;
        uint2 cv;
        cv.x = pkrtz_u32(acc[i][j][0], acc[i][j][1]);
        cv.y = pkrtz_u32(acc[i][j][2], acc[i][j][3]);
        *(uint2*)(Vt + ((size_t)(bb * 16 + hh) * 64 + dd) * 1024 + m) = cv;
      }
    }
  } else {
    float sc = (bx < 8) ? 0.1803368801111f : 1.0f;   // 0.125 * log2(e) on Q only
    for (int i = 0; i < 4; i++){
      int row = by * 128 + wm + i * 16 + g * 4;
      for (int j = 0; j < 4; j++){
        int col = bx * 128 + wn + j * 16 + li;
        for (int r = 0; r < 4; r++)
          QK[(size_t)(row + r) * 2048 + col] = f2bf(acc[i][j][r] * sc);
      }
    }
  }
}

// ---------------- kernel 3: flash attention ----------------
// block = (b, h, qb): 4 waves x 16 q = 64 q per block; m-tiles of 64.
// 2048 blocks -> 8 blocks/CU (VGPR and LDS allow it; grid no longer the cap).
// XCD swizzle: bh = id&127 so q-blocks of one (b,h) share id%8 (same XCD L2).
__global__ __launch_bounds__(256) void attn(const unsigned short* __restrict__ QK,
                                            const unsigned short* __restrict__ Vt,
                                            float* __restrict__ Out){
  __shared__ __align__(16) unsigned short Kbuf[64 * 64];   // bf16
  __shared__ __align__(16) unsigned short Vbuf[64 * 64];   // fp16
  int id = blockIdx.x;                  // 2048
  int bh = id & 127, qb = id >> 7;      // qb 0..15
  int b = bh >> 4, h = bh & 15;
  int w = threadIdx.x >> 6, lane = threadIdx.x & 63;
  int g = lane >> 4, li = lane & 15;
  int lrow = lane >> 3, lcol = lane & 7;
  int scol = ((lcol ^ lrow) & 7) * 8;   // XOR-swizzled staging column

  // Q B-frags (bf16): lane li holds col q, k = c*32 + g*8 + j
  frag_u qf[2];
  {
    int tok = b * 1024 + qb * 64 + w * 16 + li;
    const unsigned short* qp = QK + (size_t)tok * 2048 + h * 64 + g * 8;
    qf[0].u4 = *(const uint4*)(qp);
    qf[1].u4 = *(const uint4*)(qp + 32);
  }

  f32x4 o[4] = {};             // O^T tiles: row v = tv*16+g*4+r, col q = li
  float psum = 0.f;            // per-lane softmax denom (biased by 2^-10, cancels)
  const f32x4 bias = {-10.f, -10.f, -10.f, -10.f};   // fp16-overflow guard

  const unsigned short* Kg = QK + (size_t)b * 1024 * 2048 + 1024 + h * 64;
  const unsigned short* Vg = Vt + (size_t)bh * 65536;

  for (int mt = 0; mt < 16; mt++){
    int m0 = mt * 64;
    __syncthreads();                    // K/V LDS reuse barrier
    for (int i = 0; i < 2; i++){
      int idx = w * 2 + i;              // 0..7
      int row = idx * 8 + lrow;         // 0..63
      gl_lds16(Kg + (size_t)(m0 + row) * 2048 + scol, Kbuf + idx * 512);
      gl_lds16(Vg + row * 1024 + m0 + scol,           Vbuf + idx * 512);
    }
    __syncthreads();

    // S^T = K Q^T - 10 : A-frag = K rows (m) from LDS, B-frag = Q (regs)
    f32x4 s[4];
    for (int t = 0; t < 4; t++) s[t] = bias;
    for (int t = 0; t < 4; t++){
      for (int c = 0; c < 2; c++){
        frag_u kf;
        kf.u4 = *(const uint4*)(Kbuf + (t * 16 + li) * 64 + ((((c << 2) + g) ^ (li & 7)) << 3));
        s[t] = __builtin_amdgcn_mfma_f32_16x16x32_bf16(kf.f, qf[c].f, s[t], 0, 0, 0);
      }
    }

    // P = exp2(S^T); lane holds P[q=li][m = t*16 + g*4 + r] == B-frag(k = g*4+e)
    // of mfma_f32_16x16x16f16 for k-chunk t. Pack straight into registers.
    pfrag_u pf[4];
    for (int t = 0; t < 4; t++){
      float p0 = __builtin_exp2f(s[t][0]);
      float p1 = __builtin_exp2f(s[t][1]);
      float p2 = __builtin_exp2f(s[t][2]);
      float p3 = __builtin_exp2f(s[t][3]);
      psum += (p0 + p1) + (p2 + p3);
      pf[t].u[0] = pkrtz_u32(p0, p1);
      pf[t].u[1] = pkrtz_u32(p2, p3);
    }

    // O^T += V^T P^T : A-frag = V^T[v = tv*16+li][m = t*16 + g*4 + e] (b64 from
    // LDS, swizzle-aware), B-frag = pf (regs).
    for (int tv = 0; tv < 4; tv++){
      for (int t = 0; t < 4; t++){
        int gg = ((t * 2 + (g >> 1)) ^ (li & 7));
        vfrag_u vf;
        vf.u2 = *(const uint2*)(Vbuf + (tv * 16 + li) * 64 + gg * 8 + (g & 1) * 4);
        o[tv] = __builtin_amdgcn_mfma_f32_16x16x16f16(vf.f, pf[t].f, o[tv], 0, 0, 0);
      }
    }
  }

  // softmax denominator: in-lane partials + across the 4 g-groups
  psum += __shfl_xor(psum, 16);
  psum += __shfl_xor(psum, 32);
  float inv = 1.f / psum;

  // epilogue: lane holds O^T[v = tv*16+g*4+r][q=li] -> Out[b,q,h,v]; v contiguous
  int tok = b * 1024 + qb * 64 + w * 16 + li;
  float* op = Out + (size_t)tok * 1024 + h * 64 + g * 4;
  for (int tv = 0; tv < 4; tv++){
    float4 v4;
    v4.x = o[tv][0] * inv; v4.y = o[tv][1] * inv;
    v4.z = o[tv][2] * inv; v4.w = o[tv][3] * inv;
    *(float4*)(op + tv * 16) = v4;
  }
}

extern "C" void kernel_launch(void* const* d_in, const int* in_sizes, int n_in,
                              void* d_out, int out_size, void* d_ws, size_t ws_size,
                              hipStream_t stream) {
  const float* X  = (const float*)d_in[0];
  const float* Wq = (const float*)d_in[1];
  const float* Wk = (const float*)d_in[2];
  const float* Wv = (const float*)d_in[3];
  float* Out = (float*)d_out;
  char* ws = (char*)d_ws;
  // workspace layout (bytes): Xb 16MB | Wt 6MB | QK 32MB | Vt 16MB  (total 70MB)
  unsigned short* Xb = (unsigned short*)(ws);
  unsigned short* Wt = (unsigned short*)(ws + (size_t)16 * 1024 * 1024);
  unsigned short* QK = (unsigned short*)(ws + (size_t)22 * 1024 * 1024);
  unsigned short* Vt = (unsigned short*)(ws + (size_t)54 * 1024 * 1024);

  cast_all<<<8960, 256, 0, stream>>>(X, Wq, Wk, Wv, Xb, Wt);
  gemm_qkv<<<1536, 256, 0, stream>>>(Xb, Wt, QK, Vt);
  attn    <<<2048, 256, 0, stream>>>(QK, Vt, Out);
}

// Round 11
// 213.807 us; speedup vs baseline: 1.5376x; 1.0157x over previous
//
#include <hip/hip_runtime.h>
#include <stdint.h>

// B=8, W=1024, D=1024, H=16, KD=VD=64
// QK buffer: rows = token (8192), cols = proj*1024 + h*64 + d (2048; Q,K only, bf16)
// Vt[bh][d][m] fp16, written transposed from the GEMM epilogue.
// Q pre-scaled by 0.125*log2(e) (softmax in exp2 domain).
// attn: single-buffered LDS staging, P in registers (S^T C-layout ==
// 16x16x16f16 B-frag layout), softmax denominator computed BY MFMA via an
// all-ones A-fragment (no VALU adds, no shuffles).
// S^T accumulator seeded with -10 so P=exp2(s-10) stays below fp16 max.

using bf16x8 = __attribute__((ext_vector_type(8))) __bf16;
using f32x4  = __attribute__((ext_vector_type(4))) float;
using f16x4  = __attribute__((ext_vector_type(4))) _Float16;

union frag_u  { uint4 u4; bf16x8 f; };
union vfrag_u { uint2 u2; f16x4 f; };
union pfrag_u { unsigned int u[2]; f16x4 f; };

__device__ inline unsigned short f2bf(float x){
  unsigned int u = __float_as_uint(x);
  u += 0x7fffu + ((u >> 16) & 1u);      // round-to-nearest-even
  return (unsigned short)(u >> 16);
}

__device__ inline unsigned int pkrtz_u32(float a, float b){
  auto r = __builtin_amdgcn_cvt_pkrtz(a, b);   // __fp16 ext_vector(2)
  unsigned int u; __builtin_memcpy(&u, &r, 4); return u;
}

__device__ inline void gl_lds16(const void* g, void* l){
  __builtin_amdgcn_global_load_lds(
      (const __attribute__((address_space(1))) void*)g,
      (__attribute__((address_space(3))) void*)l, 16, 0, 0);
}

// ---------------- kernel 1: fused input & weight cast ----------------
// blocks [0,8192): X fp32->bf16.  blocks [8192,8960): W transpose+cast.
__global__ void cast_all(const float* __restrict__ X,
                         const float* __restrict__ Wq, const float* __restrict__ Wk,
                         const float* __restrict__ Wv,
                         unsigned short* __restrict__ Xb,
                         unsigned short* __restrict__ Wt){
  __shared__ float tile[64][65];
  int bid = blockIdx.x;
  if (bid < 8192){
    int i = (bid * 256 + threadIdx.x) * 4;
    float4 v = *(const float4*)(X + i);
    ushort4 o;
    o.x = f2bf(v.x); o.y = f2bf(v.y); o.z = f2bf(v.z); o.w = f2bf(v.w);
    *(ushort4*)(Xb + i) = o;
    return;
  }
  int id = bid - 8192;            // 0..767
  int proj = id >> 8;
  int rem  = id & 255;
  int kt = rem & 15, nt = rem >> 4;
  const float* Wsrc = (proj == 0) ? Wq : ((proj == 1) ? Wk : Wv);
  int k0 = kt * 64, n0 = nt * 64;
  int tx = threadIdx.x & 63, ty = threadIdx.x >> 6;   // ty 0..3
  for (int i = 0; i < 16; i++){
    int k = i * 4 + ty;
    tile[k][tx] = Wsrc[(k0 + k) * 1024 + n0 + tx];
  }
  __syncthreads();
  for (int i = 0; i < 16; i++){
    int n = i * 4 + ty;
    Wt[(proj * 1024 + n0 + n) * 1024 + k0 + tx] = f2bf(tile[tx][n]);
  }
}

// ---------------- kernel 2: fused QKV GEMM (m97 structure) ----------------
// n<1024 (Q): *0.125*log2(e) -> QK stride 2048 (bf16)
// 1024<=n<2048 (K): -> QK stride 2048 (bf16)
// n>=2048 (V): transposed -> Vt[bh][d][m] (fp16)
// XCD swizzle: bid = bx*64 + by, so the 24 blocks sharing one Xb row-tile
// (same by) are spaced 64 apart -> same bid%8 -> same XCD L2 (Xb fills 1x).
__global__ void gemm_qkv(const unsigned short* __restrict__ Xb,
                         const unsigned short* __restrict__ Wt,
                         unsigned short* __restrict__ QK,
                         unsigned short* __restrict__ Vt){
  __shared__ __align__(16) unsigned short Abuf[128 * 64];
  __shared__ __align__(16) unsigned short Bbuf[128 * 64];
  int bid = blockIdx.x;                 // 1536
  int bx = bid >> 6, by = bid & 63;     // bx: n-tile (24), by: m-tile (64)
  int w = threadIdx.x >> 6, lane = threadIdx.x & 63;
  int g = lane >> 4, li = lane & 15;
  int lrow = lane >> 3, lcol = lane & 7;
  int wm = (w >> 1) * 64, wn = (w & 1) * 64;
  f32x4 acc[4][4] = {};

  for (int k0 = 0; k0 < 1024; k0 += 64){
    __syncthreads();
    for (int i = 0; i < 4; i++){
      int idx = w * 4 + i;              // 0..15
      int row = idx * 8 + lrow;         // 0..127
      gl_lds16(Xb + (by * 128 + row) * 1024 + k0 + lcol * 8, Abuf + idx * 512);
      gl_lds16(Wt + (bx * 128 + row) * 1024 + k0 + lcol * 8, Bbuf + idx * 512);
    }
    __syncthreads();
    for (int c = 0; c < 2; c++){
      frag_u a[4], b[4];
      for (int i = 0; i < 4; i++)
        a[i].u4 = *(const uint4*)(Abuf + (wm + i * 16 + li) * 64 + c * 32 + g * 8);
      for (int j = 0; j < 4; j++)
        b[j].u4 = *(const uint4*)(Bbuf + (wn + j * 16 + li) * 64 + c * 32 + g * 8);
      for (int i = 0; i < 4; i++)
        for (int j = 0; j < 4; j++)
          acc[i][j] = __builtin_amdgcn_mfma_f32_16x16x32_bf16(a[i].f, b[j].f, acc[i][j], 0, 0, 0);
    }
  }
  if (bx >= 16){
    // V tiles: transposed fp16 into Vt[(b*16+h)*64*1024 + d*1024 + m]
    for (int i = 0; i < 4; i++){
      int row = by * 128 + wm + i * 16 + g * 4;     // token; r -> consecutive m
      int bb = row >> 10, m = row & 1023;
      for (int j = 0; j < 4; j++){
        int vc = bx * 128 + wn + j * 16 + li - 2048;  // v-column 0..1023
        int hh = vc >> 6, dd = vc & 63;
        uint2 cv;
        cv.x = pkrtz_u32(acc[i][j][0], acc[i][j][1]);
        cv.y = pkrtz_u32(acc[i][j][2], acc[i][j][3]);
        *(uint2*)(Vt + ((size_t)(bb * 16 + hh) * 64 + dd) * 1024 + m) = cv;
      }
    }
  } else {
    float sc = (bx < 8) ? 0.1803368801111f : 1.0f;   // 0.125 * log2(e) on Q only
    for (int i = 0; i < 4; i++){
      int row = by * 128 + wm + i * 16 + g * 4;
      for (int j = 0; j < 4; j++){
        int col = bx * 128 + wn + j * 16 + li;
        for (int r = 0; r < 4; r++)
          QK[(size_t)(row + r) * 2048 + col] = f2bf(acc[i][j][r] * sc);
      }
    }
  }
}

// ---------------- kernel 3: flash attention ----------------
// block = (b, h, qb): 4 waves x 16 q = 64 q per block; m-tiles of 64.
// 2048 blocks; launch_bounds(256,4) caps unified regs at 128/wave (4 blocks/CU).
// XCD swizzle: bh = id&127 so q-blocks of one (b,h) share id%8 (same XCD L2).
__global__ __launch_bounds__(256, 4) void attn(const unsigned short* __restrict__ QK,
                                               const unsigned short* __restrict__ Vt,
                                               float* __restrict__ Out){
  __shared__ __align__(16) unsigned short Kbuf[64 * 64];   // bf16
  __shared__ __align__(16) unsigned short Vbuf[64 * 64];   // fp16
  int id = blockIdx.x;                  // 2048
  int bh = id & 127, qb = id >> 7;      // qb 0..15
  int b = bh >> 4, h = bh & 15;
  int w = threadIdx.x >> 6, lane = threadIdx.x & 63;
  int g = lane >> 4, li = lane & 15;
  int lrow = lane >> 3, lcol = lane & 7;
  int scol = ((lcol ^ lrow) & 7) * 8;   // XOR-swizzled staging column

  // Q B-frags (bf16): lane li holds col q, k = c*32 + g*8 + j
  frag_u qf[2];
  {
    int tok = b * 1024 + qb * 64 + w * 16 + li;
    const unsigned short* qp = QK + (size_t)tok * 2048 + h * 64 + g * 8;
    qf[0].u4 = *(const uint4*)(qp);
    qf[1].u4 = *(const uint4*)(qp + 32);
  }

  f32x4 o[4] = {};             // O^T tiles: row v = tv*16+g*4+r, col q = li
  f32x4 osum = {};             // ones-row PV accumulator: every entry = psum[q=li]
  const f32x4 bias = {-10.f, -10.f, -10.f, -10.f};   // fp16-overflow guard
  pfrag_u ones;                // all-ones fp16 A-frag for the denominator MFMA
  ones.u[0] = 0x3c003c00u; ones.u[1] = 0x3c003c00u;

  const unsigned short* Kg = QK + (size_t)b * 1024 * 2048 + 1024 + h * 64;
  const unsigned short* Vg = Vt + (size_t)bh * 65536;

  for (int mt = 0; mt < 16; mt++){
    int m0 = mt * 64;
    __syncthreads();                    // K/V LDS reuse barrier
    for (int i = 0; i < 2; i++){
      int idx = w * 2 + i;              // 0..7
      int row = idx * 8 + lrow;         // 0..63
      gl_lds16(Kg + (size_t)(m0 + row) * 2048 + scol, Kbuf + idx * 512);
      gl_lds16(Vg + row * 1024 + m0 + scol,           Vbuf + idx * 512);
    }
    __syncthreads();

    // S^T = K Q^T - 10 : A-frag = K rows (m) from LDS, B-frag = Q (regs)
    f32x4 s[4];
    for (int t = 0; t < 4; t++) s[t] = bias;
    for (int t = 0; t < 4; t++){
      for (int c = 0; c < 2; c++){
        frag_u kf;
        kf.u4 = *(const uint4*)(Kbuf + (t * 16 + li) * 64 + ((((c << 2) + g) ^ (li & 7)) << 3));
        s[t] = __builtin_amdgcn_mfma_f32_16x16x32_bf16(kf.f, qf[c].f, s[t], 0, 0, 0);
      }
    }

    // P = exp2(S^T); lane holds P[q=li][m = t*16 + g*4 + r] == B-frag(k = g*4+e)
    // of mfma_f32_16x16x16f16 for k-chunk t. Pack straight into registers.
    pfrag_u pf[4];
    for (int t = 0; t < 4; t++){
      float p0 = __builtin_exp2f(s[t][0]);
      float p1 = __builtin_exp2f(s[t][1]);
      float p2 = __builtin_exp2f(s[t][2]);
      float p3 = __builtin_exp2f(s[t][3]);
      pf[t].u[0] = pkrtz_u32(p0, p1);
      pf[t].u[1] = pkrtz_u32(p2, p3);
    }

    // O^T += V^T P^T ; denominator row via ones-A MFMA (column sums of P).
    for (int t = 0; t < 4; t++)
      osum = __builtin_amdgcn_mfma_f32_16x16x16f16(ones.f, pf[t].f, osum, 0, 0, 0);
    for (int tv = 0; tv < 4; tv++){
      for (int t = 0; t < 4; t++){
        int gg = ((t * 2 + (g >> 1)) ^ (li & 7));
        vfrag_u vf;
        vf.u2 = *(const uint2*)(Vbuf + (tv * 16 + li) * 64 + gg * 8 + (g & 1) * 4);
        o[tv] = __builtin_amdgcn_mfma_f32_16x16x16f16(vf.f, pf[t].f, o[tv], 0, 0, 0);
      }
    }
  }

  // denominator: osum rows are all identical = sum_m P[q=li][m]
  float inv = 1.f / osum[0];

  // epilogue: lane holds O^T[v = tv*16+g*4+r][q=li] -> Out[b,q,h,v]; v contiguous
  int tok = b * 1024 + qb * 64 + w * 16 + li;
  float* op = Out + (size_t)tok * 1024 + h * 64 + g * 4;
  for (int tv = 0; tv < 4; tv++){
    float4 v4;
    v4.x = o[tv][0] * inv; v4.y = o[tv][1] * inv;
    v4.z = o[tv][2] * inv; v4.w = o[tv][3] * inv;
    *(float4*)(op + tv * 16) = v4;
  }
}

extern "C" void kernel_launch(void* const* d_in, const int* in_sizes, int n_in,
                              void* d_out, int out_size, void* d_ws, size_t ws_size,
                              hipStream_t stream) {
  const float* X  = (const float*)d_in[0];
  const float* Wq = (const float*)d_in[1];
  const float* Wk = (const float*)d_in[2];
  const float* Wv = (const float*)d_in[3];
  float* Out = (float*)d_out;
  char* ws = (char*)d_ws;
  // workspace layout (bytes): Xb 16MB | Wt 6MB | QK 32MB | Vt 16MB  (total 70MB)
  unsigned short* Xb = (unsigned short*)(ws);
  unsigned short* Wt = (unsigned short*)(ws + (size_t)16 * 1024 * 1024);
  unsigned short* QK = (unsigned short*)(ws + (size_t)22 * 1024 * 1024);
  unsigned short* Vt = (unsigned short*)(ws + (size_t)54 * 1024 * 1024);

  cast_all<<<8960, 256, 0, stream>>>(X, Wq, Wk, Wv, Xb, Wt);
  gemm_qkv<<<1536, 256, 0, stream>>>(Xb, Wt, QK, Vt);
  attn    <<<2048, 256, 0, stream>>>(QK, Vt, Out);
}